// Round 4
// baseline (252.848 us; speedup 1.0000x reference)
//
#include <hip/hip_runtime.h>

// InputPreprocessor — B=2048, N=32, M=8, D_PAIR=37, H=128.
// features_el_el in the reference is DEAD CODE. Live outputs (both f32):
//   out0 = features_el  [B,N,424]  (ion-summed 2-layer silu MLP || flat feats)
//   out1 = features_ion [B,8,32]
// R11: occupancy attack. R10 showed VALU cuts don't move time (latency-bound
// at 4 waves/SIMD). Changes:
//  - h0 staging becomes a ROLLING per-c-chunk buffer: layer-1 chunk c
//    (k in [32c,32c+32)) is produced exactly by l0 steps tc=2c,2c+1, so
//    write chunk -> read afk -> 8 l1 MFMAs, reuse buffer. [16][40] shorts
//    (stride-40 pad => bank-uniform b64 writes / b128 reads). UNI shrinks
//    4 KB -> 1.28 KB per wave; also interleaves l1(c) with l0(c+1) (ILP).
//  - block 1024 (16 waves): LDS = 16384+32768+16*1280 = 69632 B ->
//    2 blocks/CU = 32 waves/CU = 8 waves/SIMD (FULL occupancy), grid 512 =
//    exactly 2 blocks/CU, no tail. __launch_bounds__(1024,8) caps VGPR at 64.
//  - RBF mu/1/sigma un-hoisted (recomputed per iter) to fit the 64-VGPR cap;
//    R10 proved VALU issue is not the limiter.
// Carried: LDS h0 handoff w/ wave-private aliasing (no in-loop barriers),
// v_cvt_pk_bf16_f32 packing, bias0 via 1.0-feature, b1 hoisted, r prefetch
// pipeline, ion folded into prologue, setprio(1) around pure-MFMA l1 runs.

typedef __attribute__((ext_vector_type(8))) short short8;
typedef __attribute__((ext_vector_type(4))) float f32x4;

#define ITERS     4
#define UNITS_IT  32          // units per block-iteration (256 edges)
#define ROWLEN    424
#define OUT_EL    27787264    // 65536*424

__device__ __forceinline__ unsigned short f2bf(float f){   // prologue staging only
    unsigned int u = __builtin_bit_cast(unsigned int, f);
    u += 0x7fffu + ((u >> 16) & 1u);     // RNE
    return (unsigned short)(u >> 16);
}
__device__ __forceinline__ unsigned int cvtpk_bf16(float lo, float hi){
    unsigned int r;
    asm("v_cvt_pk_bf16_f32 %0, %1, %2" : "=v"(r) : "v"(lo), "v"(hi));
    return r;   // [15:0]=bf16(lo), [31:16]=bf16(hi), RNE
}
__device__ __forceinline__ unsigned short bf16s(float x){
    return (unsigned short)cvtpk_bf16(x, x);
}
__device__ __forceinline__ float fast_silu(float x){
    return x * __builtin_amdgcn_rcpf(1.0f + __expf(-x));
}

__global__ __launch_bounds__(1024, 8)
void el_kernel(const float* __restrict__ r,
               const float* __restrict__ Rion,
               const float* __restrict__ W0,
               const float* __restrict__ b0,
               const float* __restrict__ W1,
               const float* __restrict__ b1,
               const float* __restrict__ Z,
               const float* __restrict__ Wion,
               const float* __restrict__ bion,
               float* __restrict__ out)
{
    // MFMA-read layouts are [tile][chunk][lane64][8 shorts]: b128 = base+lane*16.
    __shared__ __align__(16) unsigned short W0L[8][2][64][8];   // 16384 B
    __shared__ __align__(16) unsigned short W1L[8][4][64][8];   // 32768 B
    // Per-wave 1280B union:
    //   shorts [0,512)   : featL  [4][16][8]  (feat^T k=0..31)   — feature phase
    //   shorts [512,640) : featbL [16][8]     (k=32..36, 37=1.0) — feature phase
    //   shorts [0,640)   : h0c rolling [16 edges][40] (chunk c)  — l0->l1 handoff
    __shared__ __align__(16) unsigned short UNI[16][640];       // 20480 B
    // total 69632 B -> 2 blocks (2048 thr) / CU = 32 waves/CU = FULL occupancy

    const int t    = threadIdx.x;
    const int lane = t & 63;
    const int w    = t >> 6;       // wave 0..15, owns units 2w,2w+1 (16 edges)
    const int quad = lane >> 4;
    const int l16  = lane & 15;

    // ---- stage W0L: A-frag for layer 0 (M=channel, K=feature) ----
    for (int i = t; i < 8*2*64*8; i += 1024){
        int j = i & 7, ln = (i >> 3) & 63, ch = (i >> 9) & 1, tc = i >> 10;
        int q = ln >> 4, n = tc*16 + (ln & 15);
        float v = 0.f;
        if (ch == 0)            v = W0[(q*8 + j)*128 + n];
        else if (q == 0){
            if      (j < 5)     v = W0[(32 + j)*128 + n];
            else if (j == 5)    v = b0[n];                 // bias via 1.0-feature
        }
        ((unsigned short*)W0L)[i] = f2bf(v);
    }
    // ---- stage W1L: B-frag for layer 1 (K=channel, N=out-channel) ----
    for (int i = t; i < 8*4*64*8; i += 1024){
        int j = i & 7, ln = (i >> 3) & 63, c = (i >> 9) & 3, tc = i >> 11;
        int k = c*32 + (ln >> 4)*8 + j, n = tc*16 + (ln & 15);
        ((unsigned short*)W1L)[i] = f2bf(W1[k*128 + n]);
    }
    // ---- featbL constant slots (iteration 0): j=5 -> 1.0, j=6,7 -> 0.
    // Raw LDS garbage on it=0 can be bf16 Inf/NaN -> 0.0*Inf = NaN in the
    // layer-0 MFMA. For it>=1 slots 6,7 hold finite h0c leftovers (x 0.0
    // weight row = exact 0); slot 5 is rewritten each iteration (phase 3).
    if (t < 256){
        UNI[t >> 4][512 + (t & 15)*8 + 5] = 0x3F80;
        UNI[t >> 4][512 + (t & 15)*8 + 6] = 0;
        UNI[t >> 4][512 + (t & 15)*8 + 7] = 0;
    }

    // ---- ion output folded in: exactly 1 element per thread (524288 total) ----
    {
        int e = blockIdx.x*1024 + t;
        int j = e & 31, mm = (e >> 5) & 7;
        out[OUT_EL + e] = fast_silu(Z[mm] * Wion[j] + bion[j]);
    }

    // feature-phase mapping: 4 threads per edge; wave-local (frow>>4 == w)
    const int frow  = t >> 2;      // edge 0..255 = ul*8 + m
    const int phase = t & 3;
    const int ul    = frow >> 3;   // block-local unit 0..31
    const int m     = frow & 7;
    const int e16   = frow & 15;   // wave-local edge
    const float Rx = Rion[m*3+0];
    const float Ry = Rion[m*3+1];
    const float Rz = Rion[m*3+2];

    unsigned short* const uw = &UNI[w][0];

    const f32x4 zeroc = {0.f,0.f,0.f,0.f};

    // hoist layer-1 bias (8 VGPRs)
    float bias1[8];
    #pragma unroll
    for (int tc = 0; tc < 8; ++tc) bias1[tc] = b1[tc*16 + l16];

    const int ubase0 = blockIdx.x * (UNITS_IT * ITERS);

    // r software pipeline: current xyz in registers, prefetched one iter ahead
    float cx, cy, cz;
    {
        int gu = ubase0 + ul;
        cx = r[gu*3+0]; cy = r[gu*3+1]; cz = r[gu*3+2];
    }

    __syncthreads();   // weights staged; loop body is wave-local (no in-loop barriers)

    for (int it = 0; it < ITERS; ++it){
        const int ubase = ubase0 + it * UNITS_IT;

        // prefetch next iteration's r (wave-uniform branch; consumed next iter)
        float nx = 0.f, ny = 0.f, nz = 0.f;
        if (it < ITERS-1){
            int gun = ubase + UNITS_IT + ul;
            nx = r[gun*3+0]; ny = r[gun*3+1]; nz = r[gun*3+2];
        }

        // ---------- features: bf16 -> featL/featbL + exact f32 -> out ----------
        {
            int gu = ubase + ul;
            float dx = cx - Rx;
            float dy = cy - Ry;
            float dz = cz - Rz;
            float d2 = dx*dx + dy*dy + dz*dz;
            float d  = __builtin_amdgcn_sqrtf(d2);
            float* orow = &out[(size_t)gu*ROWLEN + 128 + m*37];
            // RBF slots: f = phase+4k -> f>>3 = k>>1, f&7 = phase+4*(k&1)
            #pragma unroll
            for (int k = 0; k < 8; ++k){
                float q   = (float)(phase + 4*k) * (1.0f/31.0f);
                float mu  = q*q*5.0f;
                float is  = 7.0f * __builtin_amdgcn_rcpf(1.0f + 5.0f*q);
                float uu  = (d - mu) * is;
                float val = d2 * __expf(-d - uu*uu);
                orow[phase + 4*k] = val;
                uw[(k >> 1)*128 + e16*8 + phase + ((k & 1) << 2)] = bf16s(val);
            }
            // tail features (f = 32..36) + per-iter rewrite of the 1.0 slot
            if (phase == 0){
                orow[32] = d;  uw[512 + e16*8 + 0] = bf16s(d);
                orow[36] = dz; uw[512 + e16*8 + 4] = bf16s(dz);
            } else if (phase == 1){
                float v = __builtin_amdgcn_rcpf(d + 0.01f);
                orow[33] = v;  uw[512 + e16*8 + 1] = bf16s(v);
            } else if (phase == 2){
                orow[34] = dx; uw[512 + e16*8 + 2] = bf16s(dx);
            } else {
                orow[35] = dy; uw[512 + e16*8 + 3] = bf16s(dy);
                uw[512 + e16*8 + 5] = 0x3F80;
            }
        }

        // ---------- fused layer0/layer1, rolling h0 chunk ----------
        short8 bf0 = *(const short8*)&uw[quad*128 + l16*8];   // k = quad*8+j
        short8 bf1 = *(const short8*)&uw[512 + l16*8];        // k = 32+j
        // featL/featbL now dead in LDS -> h0c may overwrite the union.
        f32x4 acc1[8];
        #pragma unroll
        for (int i = 0; i < 8; ++i) acc1[i] = zeroc;

        #pragma unroll
        for (int c = 0; c < 4; ++c){
            // l0 steps tc=2c, 2c+1 produce exactly k-chunk c = [32c, 32c+32)
            #pragma unroll
            for (int h = 0; h < 2; ++h){
                const int tc = 2*c + h;
                short8 a0 = *(const short8*)&W0L[tc][0][lane][0];
                short8 a1 = *(const short8*)&W0L[tc][1][lane][0];
                f32x4 acc = __builtin_amdgcn_mfma_f32_16x16x32_bf16(a0, bf0, zeroc, 0, 0, 0);
                acc       = __builtin_amdgcn_mfma_f32_16x16x32_bf16(a1, bf1, acc,   0, 0, 0);
                // C-layout: lane holds ch n = tc*16 + quad*4 + rr, edge = l16.
                unsigned int p01 = cvtpk_bf16(fast_silu(acc[0]), fast_silu(acc[1]));
                unsigned int p23 = cvtpk_bf16(fast_silu(acc[2]), fast_silu(acc[3]));
                unsigned long long pk = (unsigned long long)p01 |
                                        ((unsigned long long)p23 << 32);
                // h0c[edge=l16][ch32 = h*16+quad*4 ..+3]; stride-40 rows =>
                // bank-uniform b64 write (32 B per bank pair, no excess)
                *(unsigned long long*)&uw[l16*40 + h*16 + quad*4] = pk;
            }
            // A-frag for chunk c: h0c[edge=l16][ch32 = quad*8 + j]
            short8 afk = *(const short8*)&uw[l16*40 + quad*8];
            __builtin_amdgcn_s_setprio(1);   // pure-MFMA run; waves are phase-diverse
            #pragma unroll
            for (int tc2 = 0; tc2 < 8; ++tc2){
                short8 bw = *(const short8*)&W1L[tc2][c][lane][0];
                acc1[tc2] = __builtin_amdgcn_mfma_f32_16x16x32_bf16(afk, bw, acc1[tc2], 0, 0, 0);
            }
            __builtin_amdgcn_s_setprio(0);
        }

        // bias + silu + ion-sum over rows, store one_el f32
        #pragma unroll
        for (int tc = 0; tc < 8; ++tc){
            float v = 0.f;
            #pragma unroll
            for (int rr = 0; rr < 4; ++rr) v += fast_silu(acc1[tc][rr] + bias1[tc]);
            v += __shfl_xor(v, 16, 64);   // quad0+1 -> unit 2w; quad2+3 -> unit 2w+1
            if ((quad & 1) == 0){
                size_t gu = (size_t)(ubase + 2*w + (quad >> 1));
                out[gu*ROWLEN + tc*16 + l16] = v;
            }
        }

        cx = nx; cy = ny; cz = nz;   // rotate r pipeline
    }
}

extern "C" void kernel_launch(void* const* d_in, const int* in_sizes, int n_in,
                              void* d_out, int out_size, void* d_ws, size_t ws_size,
                              hipStream_t stream)
{
    const float* r    = (const float*)d_in[0];
    const float* Rion = (const float*)d_in[1];
    const float* Z    = (const float*)d_in[2];
    const float* W0   = (const float*)d_in[3];
    const float* b0   = (const float*)d_in[4];
    const float* W1   = (const float*)d_in[5];
    const float* b1   = (const float*)d_in[6];
    const float* Wion = (const float*)d_in[7];
    const float* bion = (const float*)d_in[8];
    float* out = (float*)d_out;

    el_kernel<<<dim3(512), dim3(1024), 0, stream>>>(r, Rion, W0, b0, W1, b1,
                                                    Z, Wion, bion, out);
}

// Round 6
// 181.772 us; speedup vs baseline: 1.3910x; 1.3910x over previous
//
#include <hip/hip_runtime.h>

// InputPreprocessor — B=2048, N=32, M=8, D_PAIR=37, H=128.
// features_el_el in the reference is DEAD CODE. Live outputs (both f32):
//   out0 = features_el  [B,N,424]  (ion-summed 2-layer silu MLP || flat feats)
//   out1 = features_ion [B,8,32]
// R12 (resubmit — round 5 was a broker acquisition timeout, no measurement):
// cross-iteration software pipeline at proven occupancy (R11's 8-wave/SIMD
// attempt hit the register wall: 64-reg unified cap vs ~70-90 true demand ->
// 171 MB scratch spills, 2x regression).
//  - UNI split into 3 disjoint per-wave regions: featA[0,640) / featB[640,1280)
//    double-buffer + rolling h0c[1280,1920) (stride-40 rows; b64 writes and
//    b128 reads both bank-uniform). No aliasing -> bias/zero slots init ONCE.
//  - Body(it): read bf frags from cur; compute feat((it+1)&7) into cur^640;
//    fused l0/l1 c-loop; epilogue. Fully BRANCHLESS body (feature tails via
//    selects, idempotent last-iter feat(0) recompute, wrapped r prefetch) ->
//    one scheduling region so the compiler interleaves independent feat
//    VALU/trans work into l0/l1 MFMA and lgkmcnt stall slots.
//  - LDS = 16384+32768+30720 = 79872 B -> 2 blocks (512 thr)/CU, 16 waves/CU
//    as R10. __launch_bounds__(512,4) caps VGPR at 128 (no spills; demand ~90).
// Carried from R10/R11: rolling h0c l0->l1 handoff (wave-private, in-loop
// barrier-free), v_cvt_pk_bf16_f32 packing, bias0 via 1.0-feature, b1/mu/sigma
// hoisted, 2-deep r prefetch, ion folded into prologue, setprio around l1.

typedef __attribute__((ext_vector_type(8))) short short8;
typedef __attribute__((ext_vector_type(4))) float f32x4;

#define ITERS     8
#define UNITS_IT  16          // units per block-iteration (128 edges)
#define ROWLEN    424
#define OUT_EL    27787264    // 65536*424

__device__ __forceinline__ unsigned short f2bf(float f){   // prologue staging only
    unsigned int u = __builtin_bit_cast(unsigned int, f);
    u += 0x7fffu + ((u >> 16) & 1u);     // RNE
    return (unsigned short)(u >> 16);
}
__device__ __forceinline__ unsigned int cvtpk_bf16(float lo, float hi){
    unsigned int r;
    asm("v_cvt_pk_bf16_f32 %0, %1, %2" : "=v"(r) : "v"(lo), "v"(hi));
    return r;   // [15:0]=bf16(lo), [31:16]=bf16(hi), RNE
}
__device__ __forceinline__ unsigned short bf16s(float x){
    return (unsigned short)cvtpk_bf16(x, x);
}
__device__ __forceinline__ float fast_silu(float x){
    return x * __builtin_amdgcn_rcpf(1.0f + __expf(-x));
}

__global__ __launch_bounds__(512, 4)
void el_kernel(const float* __restrict__ r,
               const float* __restrict__ Rion,
               const float* __restrict__ W0,
               const float* __restrict__ b0,
               const float* __restrict__ W1,
               const float* __restrict__ b1,
               const float* __restrict__ Z,
               const float* __restrict__ Wion,
               const float* __restrict__ bion,
               float* __restrict__ out)
{
    // MFMA-read layouts are [tile][chunk][lane64][8 shorts]: b128 = base+lane*16.
    __shared__ __align__(16) unsigned short W0L[8][2][64][8];   // 16384 B
    __shared__ __align__(16) unsigned short W1L[8][4][64][8];   // 32768 B
    // Per-wave 3840B, three DISJOINT regions (no aliasing, no barriers):
    //   shorts [0,640)     : featA (k<32: [4][16][8]; tails+1.0+pad: [16][8])
    //   shorts [640,1280)  : featB (same layout; double buffer)
    //   shorts [1280,1920) : h0c rolling [16 edges][40] (l0->l1 chunk handoff)
    __shared__ __align__(16) unsigned short UNI[8][1920];       // 30720 B
    // total 79872 B -> 2 blocks (1024 thr) / CU = 16 waves/CU

    const int t    = threadIdx.x;
    const int lane = t & 63;
    const int w    = t >> 6;       // wave 0..7, owns units 2w,2w+1 (16 edges)
    const int quad = lane >> 4;
    const int l16  = lane & 15;

    // ---- stage W0L: A-frag for layer 0 (M=channel, K=feature) ----
    for (int i = t; i < 8*2*64*8; i += 512){
        int j = i & 7, ln = (i >> 3) & 63, ch = (i >> 9) & 1, tc = i >> 10;
        int q = ln >> 4, n = tc*16 + (ln & 15);
        float v = 0.f;
        if (ch == 0)            v = W0[(q*8 + j)*128 + n];
        else if (q == 0){
            if      (j < 5)     v = W0[(32 + j)*128 + n];
            else if (j == 5)    v = b0[n];                 // bias via 1.0-feature
        }
        ((unsigned short*)W0L)[i] = f2bf(v);
    }
    // ---- stage W1L: B-frag for layer 1 (K=channel, N=out-channel) ----
    for (int i = t; i < 8*4*64*8; i += 512){
        int j = i & 7, ln = (i >> 3) & 63, c = (i >> 9) & 3, tc = i >> 11;
        int k = c*32 + (ln >> 4)*8 + j, n = tc*16 + (ln & 15);
        ((unsigned short*)W1L)[i] = f2bf(W1[k*128 + n]);
    }
    // ---- constant tail slots, BOTH feat buffers, once (no aliasing now):
    // slot 5 = 1.0 (bias feature), slots 6,7 = 0.0 (k=38,39 pad).
    if (t < 128){
        int ww = t >> 4, e = t & 15;
        #pragma unroll
        for (int b = 0; b < 2; ++b){
            UNI[ww][b*640 + 512 + e*8 + 5] = 0x3F80;
            UNI[ww][b*640 + 512 + e*8 + 6] = 0;
            UNI[ww][b*640 + 512 + e*8 + 7] = 0;
        }
    }

    // ---- ion output folded in: 2 elements per thread (524288 total) ----
    {
        int e0 = (blockIdx.x*512 + t)*2;           // even -> j0 < 31, no wrap
        int j0 = e0 & 31, mm = (e0 >> 5) & 7;
        float z = Z[mm];
        float2 v;
        v.x = fast_silu(z * Wion[j0]     + bion[j0]);
        v.y = fast_silu(z * Wion[j0 + 1] + bion[j0 + 1]);
        *(float2*)&out[OUT_EL + e0] = v;
    }

    // feature-phase mapping: 4 threads per edge; wave-local (frow>>4 == w)
    const int frow  = t >> 2;      // edge 0..127 = ul*8 + m
    const int phase = t & 3;
    const int ul    = frow >> 3;   // block-local unit 0..15
    const int m     = frow & 7;
    const int e16   = frow & 15;   // wave-local edge
    const float Rx = Rion[m*3+0];
    const float Ry = Rion[m*3+1];
    const float Rz = Rion[m*3+2];

    unsigned short* const uw = &UNI[w][0];

    const f32x4 zeroc = {0.f,0.f,0.f,0.f};

    // hoist layer-1 bias (8 VGPRs)
    float bias1[8];
    #pragma unroll
    for (int tc = 0; tc < 8; ++tc) bias1[tc] = b1[tc*16 + l16];

    // hoist per-thread RBF constants: f = phase + 4k, k = 0..7
    float muA[8], isA[8];
    #pragma unroll
    for (int kk = 0; kk < 8; ++kk){
        float q = (float)(phase + 4*kk) * (1.0f/31.0f);
        muA[kk] = q*q*5.0f;
        isA[kk] = 7.0f * __builtin_amdgcn_rcpf(1.0f + 5.0f*q);
    }

    const int ubase0 = blockIdx.x * (UNITS_IT * ITERS);

    // Branchless feature pass: computes edge (gu, m)'s 37 features, stores
    // exact f32 to out and bf16 to feat buffer at short-offset fb.
    auto feat_pass = [&](int gu, int fb, float px, float py, float pz){
        float dx = px - Rx, dy = py - Ry, dz = pz - Rz;
        float d2 = dx*dx + dy*dy + dz*dz;
        float d  = __builtin_amdgcn_sqrtf(d2);
        float* orow = &out[(size_t)gu*ROWLEN + 128 + m*37];
        #pragma unroll
        for (int kk = 0; kk < 8; ++kk){
            float uu  = (d - muA[kk]) * isA[kk];
            float val = d2 * __expf(-d - uu*uu);
            orow[phase + 4*kk] = val;
            uw[fb + (kk >> 1)*128 + e16*8 + phase + ((kk & 1) << 2)] = bf16s(val);
        }
        // tails, branchless: this phase's slot + redundant dz (idempotent x4)
        float tv = (phase == 0) ? d :
                   (phase == 1) ? __builtin_amdgcn_rcpf(d + 0.01f) :
                   (phase == 2) ? dx : dy;
        orow[32 + phase] = tv;
        orow[36]         = dz;
        uw[fb + 512 + e16*8 + phase] = bf16s(tv);
        uw[fb + 512 + e16*8 + 4]     = bf16s(dz);
    };

    // ---- prologue: feat(0) into featA; prefetch r(1) ----
    {
        int gu = ubase0 + ul;
        feat_pass(gu, 0, r[gu*3+0], r[gu*3+1], r[gu*3+2]);
    }
    float cx, cy, cz;
    {
        int gu = ubase0 + UNITS_IT + ul;     // r(1) (ITERS>=2)
        cx = r[gu*3+0]; cy = r[gu*3+1]; cz = r[gu*3+2];
    }

    __syncthreads();   // weights staged; loop body is wave-local, barrier-free

    int cur = 0;       // short-offset of current feat buffer (0 or 640)
    for (int it = 0; it < ITERS; ++it){
        const int ubase = ubase0 + it * UNITS_IT;

        // prefetch r((it+2) & 7) — wrapped, branchless (last iters re-load r(0/1))
        int gun = ubase0 + (((it + 2) & (ITERS-1)) * UNITS_IT) + ul;
        float nx = r[gun*3+0], ny = r[gun*3+1], nz = r[gun*3+2];

        // current iteration's B-frags (featA/B[cur]; written a full iter ago)
        short8 bf0 = *(const short8*)&uw[cur + quad*128 + l16*8];   // k = quad*8+j
        short8 bf1 = *(const short8*)&uw[cur + 512 + l16*8];        // k = 32+j

        // feat for (it+1)&7 into the OTHER buffer. it=ITERS-1 recomputes
        // feat(0) with identical values (idempotent stores) — keeps the body
        // branchless so the scheduler can interleave it with l0/l1 below.
        {
            int gu = ubase0 + (((it + 1) & (ITERS-1)) * UNITS_IT) + ul;
            feat_pass(gu, cur ^ 640, cx, cy, cz);
        }

        // ---------- fused layer0/layer1, rolling h0 chunk ----------
        f32x4 acc1[8];
        #pragma unroll
        for (int i = 0; i < 8; ++i) acc1[i] = zeroc;

        #pragma unroll
        for (int c = 0; c < 4; ++c){
            // l0 steps tc=2c, 2c+1 produce exactly k-chunk c = [32c, 32c+32)
            #pragma unroll
            for (int h = 0; h < 2; ++h){
                const int tc = 2*c + h;
                short8 a0 = *(const short8*)&W0L[tc][0][lane][0];
                short8 a1 = *(const short8*)&W0L[tc][1][lane][0];
                f32x4 acc = __builtin_amdgcn_mfma_f32_16x16x32_bf16(a0, bf0, zeroc, 0, 0, 0);
                acc       = __builtin_amdgcn_mfma_f32_16x16x32_bf16(a1, bf1, acc,   0, 0, 0);
                // C-layout: lane holds ch n = tc*16 + quad*4 + rr, edge = l16.
                unsigned int p01 = cvtpk_bf16(fast_silu(acc[0]), fast_silu(acc[1]));
                unsigned int p23 = cvtpk_bf16(fast_silu(acc[2]), fast_silu(acc[3]));
                unsigned long long pk = (unsigned long long)p01 |
                                        ((unsigned long long)p23 << 32);
                // h0c[edge=l16][ch32 = h*16+quad*4 ..+3]; stride-40 rows:
                // b64 write = 4 accesses/bank uniform (conflict-free)
                *(unsigned long long*)&uw[1280 + l16*40 + h*16 + quad*4] = pk;
            }
            // A-frag chunk c: h0c[edge=l16][ch32 = quad*8 + j]
            // b128 read = 8 accesses/bank uniform (conflict-free)
            short8 afk = *(const short8*)&uw[1280 + l16*40 + quad*8];
            __builtin_amdgcn_s_setprio(1);   // pure-MFMA run; waves phase-diverse
            #pragma unroll
            for (int tc2 = 0; tc2 < 8; ++tc2){
                short8 bw = *(const short8*)&W1L[tc2][c][lane][0];
                acc1[tc2] = __builtin_amdgcn_mfma_f32_16x16x32_bf16(afk, bw, acc1[tc2], 0, 0, 0);
            }
            __builtin_amdgcn_s_setprio(0);
        }

        // bias + silu + ion-sum over rows, store one_el f32
        #pragma unroll
        for (int tc = 0; tc < 8; ++tc){
            float v = 0.f;
            #pragma unroll
            for (int rr = 0; rr < 4; ++rr) v += fast_silu(acc1[tc][rr] + bias1[tc]);
            v += __shfl_xor(v, 16, 64);   // quad0+1 -> unit 2w; quad2+3 -> unit 2w+1
            if ((quad & 1) == 0){
                size_t gu = (size_t)(ubase + 2*w + (quad >> 1));
                out[gu*ROWLEN + tc*16 + l16] = v;
            }
        }

        cur ^= 640;                    // swap feat buffers
        cx = nx; cy = ny; cz = nz;     // rotate r pipeline
    }
}

extern "C" void kernel_launch(void* const* d_in, const int* in_sizes, int n_in,
                              void* d_out, int out_size, void* d_ws, size_t ws_size,
                              hipStream_t stream)
{
    const float* r    = (const float*)d_in[0];
    const float* Rion = (const float*)d_in[1];
    const float* Z    = (const float*)d_in[2];
    const float* W0   = (const float*)d_in[3];
    const float* b0   = (const float*)d_in[4];
    const float* W1   = (const float*)d_in[5];
    const float* b1   = (const float*)d_in[6];
    const float* Wion = (const float*)d_in[7];
    const float* bion = (const float*)d_in[8];
    float* out = (float*)d_out;

    el_kernel<<<dim3(512), dim3(512), 0, stream>>>(r, Rion, W0, b0, W1, b1,
                                                   Z, Wion, bion, out);
}